// Round 4
// baseline (1063.432 us; speedup 1.0000x reference)
//
#include <hip/hip_runtime.h>
#include <math.h>

// LearnableVisitEncoder — 2-kernel pipeline, all fp32:
//   A vocab_fused : emb[20000,128] -> H2 = silu(silu(emb@W1+b1)@W2+b2) (stored)
//                   L[r] = tanh(H2@Wa1+ba1) . wa2 + ba2                (stored)
//   B pool_rho    : per visit masked softmax over L[ids],
//                   h_pool = sum a_c H2[id_c]  (LDS),
//                   out = silu(h_pool@Wr1+br1)@Wr2 + br2
//
// GEMM: wave-column-split, MT=16 rows/block. Grid: vocab 1250 blocks
// (4.9/CU), visits 1024 (4.0/CU) — round-3's 625-block grid capped
// occupancy at 24% (2.44 waves/SIMD, VALUBusy 31%). k-loop uses explicit
// distance-1 register ping-pong prefetch (VGPRs are free here; round-3's
// VGPR=52 showed the compiler wasn't pipelining the loads).

#define DIM 128
#define MT 16
#define LDP 132   // LDS row stride (528 B), 16B-aligned

__device__ __forceinline__ float silu_f(float v) {
  return v / (1.0f + expf(-v));
}

// stage 16 x 128 fp32 rows (contiguous global) into LDS tile
__device__ __forceinline__ void stage16(const float* __restrict__ src,
                                        float (*dst)[LDP], int tid) {
  const float4* s = (const float4*)src;
#pragma unroll
  for (int t = 0; t < 2; ++t) {
    int idx = tid + t * 256;          // 0..511 float4s = 16 rows x 32
    int r = idx >> 5, c4 = idx & 31;
    *(float4*)&dst[r][c4 * 4] = s[idx];
  }
}

#define FMA2(xs0, xs1, wv)                                                  \
  acc[0][0] = fmaf(xs0, wv.x, acc[0][0]);                                   \
  acc[0][1] = fmaf(xs0, wv.y, acc[0][1]);                                   \
  acc[0][2] = fmaf(xs0, wv.z, acc[0][2]);                                   \
  acc[0][3] = fmaf(xs0, wv.w, acc[0][3]);                                   \
  acc[1][0] = fmaf(xs1, wv.x, acc[1][0]);                                   \
  acc[1][1] = fmaf(xs1, wv.y, acc[1][1]);                                   \
  acc[1][2] = fmaf(xs1, wv.z, acc[1][2]);                                   \
  acc[1][3] = fmaf(xs1, wv.w, acc[1][3]);

// acc[2][4] = sIn[r0..r0+1][:] @ W[:][4*cg..4*cg+3]
// explicit distance-1 ping-pong prefetch; k applied strictly in order
// (bitwise-identical accumulation to previous rounds)
__device__ __forceinline__ void gemm_wave16(const float (*sIn)[LDP],
                                            const float* __restrict__ Wg,
                                            int cg, int r0, float acc[2][4]) {
#pragma unroll
  for (int i = 0; i < 2; ++i)
#pragma unroll
    for (int j = 0; j < 4; ++j) acc[i][j] = 0.f;
  const float4* Wv = (const float4*)Wg;  // W[k][c]: float4 index k*32 + cg
  float4 xb0[2], xb1[2], wb0[2], wb1[2], wb2[2], wb3[2];
  xb0[0] = *(const float4*)&sIn[r0 + 0][0];
  xb1[0] = *(const float4*)&sIn[r0 + 1][0];
  wb0[0] = Wv[0 * 32 + cg];
  wb1[0] = Wv[1 * 32 + cg];
  wb2[0] = Wv[2 * 32 + cg];
  wb3[0] = Wv[3 * 32 + cg];
#pragma unroll 8
  for (int c = 0; c < 32; ++c) {
    const int cur = c & 1, nxt = cur ^ 1;
    if (c < 31) {
      const int k0 = (c + 1) * 4;
      xb0[nxt] = *(const float4*)&sIn[r0 + 0][k0];
      xb1[nxt] = *(const float4*)&sIn[r0 + 1][k0];
      wb0[nxt] = Wv[(k0 + 0) * 32 + cg];
      wb1[nxt] = Wv[(k0 + 1) * 32 + cg];
      wb2[nxt] = Wv[(k0 + 2) * 32 + cg];
      wb3[nxt] = Wv[(k0 + 3) * 32 + cg];
    }
    FMA2(xb0[cur].x, xb1[cur].x, wb0[cur])
    FMA2(xb0[cur].y, xb1[cur].y, wb1[cur])
    FMA2(xb0[cur].z, xb1[cur].z, wb2[cur])
    FMA2(xb0[cur].w, xb1[cur].w, wb3[cur])
  }
}

// ---------------- Kernel A: vocab side, fully fused ----------------
__global__ __launch_bounds__(256, 4) void vocab_fused(
    const float* __restrict__ emb, const float* __restrict__ W1,
    const float* __restrict__ b1, const float* __restrict__ W2,
    const float* __restrict__ b2, const float* __restrict__ Wa1,
    const float* __restrict__ ba1, const float* __restrict__ wa2,
    const float* __restrict__ ba2, float* __restrict__ H2,
    float* __restrict__ L) {
  __shared__ float sA[MT][LDP], sB[MT][LDP];
  __shared__ float sP[4][MT];
  const int tid = threadIdx.x;
  const int wid = tid >> 6, lane = tid & 63;
  const int cg = wid * 8 + (lane & 7);  // float4-col index 0..31
  const int c0 = cg * 4;
  const int r0 = (lane >> 3) * 2;       // 8 row-groups x 2 rows
  const int m0 = blockIdx.x * MT;

  stage16(emb + (size_t)m0 * DIM, sA, tid);
  __syncthreads();

  float acc[2][4];
  // layer 1: silu(emb@W1+b1) -> sB (this wave's 32-col slice)
  gemm_wave16(sA, W1, cg, r0, acc);
  {
    float4 bv = ((const float4*)b1)[cg];
#pragma unroll
    for (int i = 0; i < 2; ++i) {
      float4 o;
      o.x = silu_f(acc[i][0] + bv.x);
      o.y = silu_f(acc[i][1] + bv.y);
      o.z = silu_f(acc[i][2] + bv.z);
      o.w = silu_f(acc[i][3] + bv.w);
      *(float4*)&sB[r0 + i][c0] = o;
    }
  }
  __syncthreads();
  // layer 2: silu(sB@W2+b2) -> sA + global H2
  gemm_wave16(sB, W2, cg, r0, acc);
  {
    float4 bv = ((const float4*)b2)[cg];
#pragma unroll
    for (int i = 0; i < 2; ++i) {
      float4 o;
      o.x = silu_f(acc[i][0] + bv.x);
      o.y = silu_f(acc[i][1] + bv.y);
      o.z = silu_f(acc[i][2] + bv.z);
      o.w = silu_f(acc[i][3] + bv.w);
      *(float4*)&sA[r0 + i][c0] = o;
      *(float4*)&H2[(size_t)(m0 + r0 + i) * DIM + c0] = o;
    }
  }
  __syncthreads();
  // layer 3: tanh(sA@Wa1+ba1) . wa2 + ba2 -> L (rowdot fused)
  gemm_wave16(sA, Wa1, cg, r0, acc);
  {
    float4 bv = ((const float4*)ba1)[cg];
    float4 wv = ((const float4*)wa2)[cg];
#pragma unroll
    for (int i = 0; i < 2; ++i) {
      float g0 = tanhf(acc[i][0] + bv.x);
      float g1 = tanhf(acc[i][1] + bv.y);
      float g2 = tanhf(acc[i][2] + bv.z);
      float g3 = tanhf(acc[i][3] + bv.w);
      float p = fmaf(g0, wv.x, fmaf(g1, wv.y, fmaf(g2, wv.z, g3 * wv.w)));
#pragma unroll
      for (int m = 1; m <= 4; m <<= 1) p += __shfl_xor(p, m, 64);  // 8 cgs
      if ((lane & 7) == 0) sP[wid][r0 + i] = p;
    }
  }
  __syncthreads();
  if (tid < MT)
    L[m0 + tid] = sP[0][tid] + sP[1][tid] + sP[2][tid] + sP[3][tid] + ba2[0];
}

// ---------------- Kernel B: pool + rho fused ----------------
// Phase 1: each wave pools 4 visits (masked softmax + gathered weighted sum)
// into LDS rows. Phase 2: 2-layer rho GEMM on the 16-visit LDS tile.
__global__ __launch_bounds__(256, 4) void pool_rho(
    const int* __restrict__ ids, const float* __restrict__ L,
    const float* __restrict__ H2, const float* __restrict__ Wr1,
    const float* __restrict__ br1, const float* __restrict__ Wr2,
    const float* __restrict__ br2, float* __restrict__ out) {
  __shared__ float sA[MT][LDP], sB[MT][LDP];
  const int tid = threadIdx.x;
  const int wid = tid >> 6, lane = tid & 63;
  const int m0 = blockIdx.x * MT;
  const int half = lane >> 5, li = lane & 31;

  for (int t = 0; t < 4; ++t) {
    const int vloc = wid * 4 + t;
    const int v = m0 + vloc;
    int id = 0;
    float lg = -3.4e38f;
    if (lane < 48) {
      id = ids[(size_t)v * 48 + lane];
      if (id != 0) lg = L[id];   // PAD_IDX==0 masked
    }
    float mx = lg;
#pragma unroll
    for (int m = 32; m; m >>= 1) mx = fmaxf(mx, __shfl_xor(mx, m, 64));
    float e = (lg > -3.0e38f) ? expf(lg - mx) : 0.f;
    float s = e;
#pragma unroll
    for (int m = 32; m; m >>= 1) s += __shfl_xor(s, m, 64);
    const float a = e / s;          // pads: exactly 0

    float4 acc = make_float4(0.f, 0.f, 0.f, 0.f);
#pragma unroll 8
    for (int c = 0; c < 24; ++c) {  // lanes 0-31: even codes, 32-63: odd
      const int cc = 2 * c + half;
      const float ac = __shfl(a, cc, 64);
      const int idc = __shfl(id, cc, 64);
      const float4 h = ((const float4*)(H2 + (size_t)idc * DIM))[li];
      acc.x = fmaf(ac, h.x, acc.x); // pad: ac==0 exactly -> no-op
      acc.y = fmaf(ac, h.y, acc.y);
      acc.z = fmaf(ac, h.z, acc.z);
      acc.w = fmaf(ac, h.w, acc.w);
    }
    acc.x += __shfl_xor(acc.x, 32, 64);
    acc.y += __shfl_xor(acc.y, 32, 64);
    acc.z += __shfl_xor(acc.z, 32, 64);
    acc.w += __shfl_xor(acc.w, 32, 64);
    if (half == 0) *(float4*)&sA[vloc][li * 4] = acc;
  }
  __syncthreads();

  // rho: out = silu(sA@Wr1+br1)@Wr2 + br2
  const int cg = wid * 8 + (lane & 7);
  const int c0 = cg * 4;
  const int r0 = (lane >> 3) * 2;
  float acc[2][4];
  gemm_wave16(sA, Wr1, cg, r0, acc);
  {
    float4 bv = ((const float4*)br1)[cg];
#pragma unroll
    for (int i = 0; i < 2; ++i) {
      float4 o;
      o.x = silu_f(acc[i][0] + bv.x);
      o.y = silu_f(acc[i][1] + bv.y);
      o.z = silu_f(acc[i][2] + bv.z);
      o.w = silu_f(acc[i][3] + bv.w);
      *(float4*)&sB[r0 + i][c0] = o;
    }
  }
  __syncthreads();
  gemm_wave16(sB, Wr2, cg, r0, acc);
  {
    float4 bv = ((const float4*)br2)[cg];
#pragma unroll
    for (int i = 0; i < 2; ++i) {
      float4 o;
      o.x = acc[i][0] + bv.x;
      o.y = acc[i][1] + bv.y;
      o.z = acc[i][2] + bv.z;
      o.w = acc[i][3] + bv.w;
      *(float4*)&out[(size_t)(m0 + r0 + i) * DIM + c0] = o;
    }
  }
}

extern "C" void kernel_launch(void* const* d_in, const int* in_sizes, int n_in,
                              void* d_out, int out_size, void* d_ws,
                              size_t ws_size, hipStream_t stream) {
  const int*   ids = (const int*)  d_in[0];
  const float* emb = (const float*)d_in[1];
  const float* W1  = (const float*)d_in[2];
  const float* b1  = (const float*)d_in[3];
  const float* W2  = (const float*)d_in[4];
  const float* b2  = (const float*)d_in[5];
  const float* Wa1 = (const float*)d_in[6];
  const float* ba1 = (const float*)d_in[7];
  const float* wa2 = (const float*)d_in[8];
  const float* ba2 = (const float*)d_in[9];
  const float* Wr1 = (const float*)d_in[10];
  const float* br1 = (const float*)d_in[11];
  const float* Wr2 = (const float*)d_in[12];
  const float* br2 = (const float*)d_in[13];
  float* out = (float*)d_out;

  const int VOCAB = 20000, V = 16384;

  float* H2 = (float*)d_ws;                       // 20000*128
  float* L  = H2 + (size_t)VOCAB * DIM;           // 20000

  vocab_fused<<<VOCAB / MT, 256, 0, stream>>>(emb, W1, b1, W2, b2, Wa1, ba1,
                                              wa2, ba2, H2, L);
  pool_rho<<<V / MT, 256, 0, stream>>>(ids, L, H2, Wr1, br1, Wr2, br2, out);
}